// Round 7
// baseline (205.109 us; speedup 1.0000x reference)
//
#include <hip/hip_runtime.h>
#include <math.h>

// Problem constants (x: [32, 256, 56, 56] fp32)
#define B_    32
#define C_    256
#define H_    56
#define W_    56
#define HW_   3136
#define HW4_  784               // float4 per channel plane
#define NF4_  25088             // B_*HW4_ f4 gate positions

typedef float f4v __attribute__((ext_vector_type(4)));

static __device__ __forceinline__ f4v f4max(f4v a, f4v b) {
  return (f4v){fmaxf(a.x, b.x), fmaxf(a.y, b.y), fmaxf(a.z, b.z), fmaxf(a.w, b.w)};
}

// ---------------------------------------------------------------------------
// K1: unchanged from R6 (1-KB contiguous wave segments; R6 A/B vs R0 showed
// segment width is neutral -> K1 is ~BW/latency-fine either way).
// ---------------------------------------------------------------------------
__global__ __launch_bounds__(512) void k1_reduce_linear(
    const float* __restrict__ x, float* __restrict__ pool) {
  const int t = threadIdx.x;
  const int lane = t & 63;
  const int w = t >> 6;                       // wave 0..7
  const unsigned if4 = (unsigned)blockIdx.x * 64u + (unsigned)lane;  // < 25088
  const unsigned bimg = if4 / 784u;
  const unsigned hw4 = if4 % 784u;
  const f4v* __restrict__ x4 = (const f4v*)x;
  const unsigned base0 = bimg * (256u * 784u) + hw4;

  f4v s = {0.f, 0.f, 0.f, 0.f};
  f4v m = {-INFINITY, -INFINITY, -INFINITY, -INFINITY};
#pragma unroll 8
  for (int k = 0; k < 32; ++k) {              // c = w + 8k
    const unsigned c = (unsigned)w + 8u * (unsigned)k;
    f4v v = x4[base0 + c * 784u];
    s += v;
    m = f4max(m, v);
  }

  __shared__ f4v ssum[8][64];                 // 8 KB
  __shared__ f4v smax[8][64];                 // 8 KB
  ssum[w][lane] = s;
  smax[w][lane] = m;
  __syncthreads();

  if (t < 64) {
    f4v S = ssum[0][t];
    f4v M = smax[0][t];
#pragma unroll
    for (int g = 1; g < 8; ++g) {
      S += ssum[g][t];
      M = f4max(M, smax[g][t]);
    }
    f4v* p4 = (f4v*)pool;
    const unsigned jf4 = (unsigned)blockIdx.x * 64u + (unsigned)t;
    const unsigned bb = jf4 / 784u;
    const unsigned hh = jf4 % 784u;
    p4[bb * 1568u + hh]        = S * (1.0f / 256.0f);  // avg plane
    p4[bb * 1568u + 784u + hh] = M;                    // max plane
  }
}

// ---------------------------------------------------------------------------
// K2: SINGLE-VARIABLE A/B vs R6 — nontemporal store -> PLAIN store for out.
// Every config R0..R6 used NT stores (never isolated); fill hits 6.85 TB/s
// with normal stores while our kernels never beat ~2 TB/s effective. Theory:
// nt bypasses L2 write-aggregation -> slow drain (R4: 1.6 TB/s, VALUBusy
// 1.75% = stalled on stores, not loads). L3 residency concern is moot:
// x (103 MB) + out (103 MB) < 256 MB L3.
// Everything else byte-identical to R6's sa_conv_apply_kernel.
// ---------------------------------------------------------------------------
__global__ __launch_bounds__(256) void sa_conv_apply_kernel(
    const float* __restrict__ x, const float* __restrict__ pool,
    const float* __restrict__ wt, float* __restrict__ out) {
  const int t = threadIdx.x;
  __shared__ float partial[128];
  __shared__ f4v sgate4[16];
  if (t < 128) {
    const int pos = t >> 1;
    const int ic = t & 1;
    const unsigned p = (unsigned)blockIdx.x * 64u + (unsigned)pos;
    const unsigned bimg = p / 3136u;
    const unsigned hw = p % 3136u;
    const int h = (int)(hw / 56u);
    const int w = (int)(hw % 56u);
    const float* pl = pool + ((long)bimg * 2 + ic) * 3136;
    const float* wr0 = wt + ic * 49;
    float acc = 0.f;
#pragma unroll
    for (int kh = 0; kh < 7; ++kh) {
      const int ih = h + kh - 3;
      if (ih < 0 || ih >= 56) continue;
      const float* row = pl + ih * 56;
      const float* wr = wr0 + kh * 7;
#pragma unroll
      for (int kw = 0; kw < 7; ++kw) {
        const int iw = w + kw - 3;
        if (iw < 0 || iw >= 56) continue;
        acc = fmaf(row[iw], wr[kw], acc);
      }
    }
    partial[t] = acc;
  }
  __syncthreads();
  if (t < 64) {
    float a = partial[2 * t] + partial[2 * t + 1];
    ((float*)sgate4)[t] = 1.0f / (1.0f + __expf(-a));
  }
  __syncthreads();

  const int lane = t & 15;
  const int cgrp = t >> 4;
  const unsigned if4 = (unsigned)blockIdx.x * 16u + (unsigned)lane;
  const unsigned bimg = if4 / 784u;
  const unsigned hw4 = if4 % 784u;
  const unsigned base = (bimg * 256u + (unsigned)cgrp) * 784u + hw4;
  const f4v* __restrict__ x4 = (const f4v*)x;
  f4v* __restrict__ o4 = (f4v*)out;
  const f4v g = sgate4[lane];
#pragma unroll 8
  for (int kk = 0; kk < 16; ++kk) {
    const unsigned idx = base + (unsigned)(kk * 16) * 784u;
    f4v v = x4[idx];
    o4[idx] = v * g;                          // PLAIN store (was NT)
  }
}

extern "C" void kernel_launch(void* const* d_in, const int* in_sizes, int n_in,
                              void* d_out, int out_size, void* d_ws, size_t ws_size,
                              hipStream_t stream) {
  const float* x  = (const float*)d_in[0];   // [32,256,56,56]
  const float* wc = (const float*)d_in[1];   // [1,2,7,7]
  float* out = (float*)d_out;
  float* pool = (float*)d_ws;                // [B,2,HW] = 802,816 B

  k1_reduce_linear<<<392, 512, 0, stream>>>(x, pool);
  sa_conv_apply_kernel<<<1568, 256, 0, stream>>>(x, pool, wc, out);
}